// Round 7
// baseline (203.008 us; speedup 1.0000x reference)
//
#include <hip/hip_runtime.h>
#include <hip/hip_bf16.h>
#include <stdint.h>

// Problem sizes (compile-time)
static constexpr int BATCH = 32768;
static constexpr int DIN   = 512;
static constexpr int DHID  = 1024;
static constexpr int DOUT  = 2048;

typedef __bf16 bf16x8 __attribute__((ext_vector_type(8)));
typedef float  f32x4  __attribute__((ext_vector_type(4)));

// fp32 -> bf16 round-to-nearest-even
__device__ __forceinline__ unsigned short f2bf(float f) {
    unsigned int u = __float_as_uint(f);
    u += 0x7FFFu + ((u >> 16) & 1u);
    return (unsigned short)(u >> 16);
}

// async global->LDS, 16B per lane. LDS dest = WAVE-uniform base + 16*(lane&63).
__device__ __forceinline__ void gload_lds16(const void* g, void* l) {
    __builtin_amdgcn_global_load_lds((__attribute__((address_space(1))) void*)g,
                                     (__attribute__((address_space(3))) void*)l,
                                     16, 0, 0);
}

// ===========================================================================
// scores = x @ W^T + b' (algebraic fusion; absmax 0.03125 measured)
// r21: 2-BLOCK-PER-CU gemmS. r19's phase = 1356 cyc = 770 (LDS reads) +
// 620 (MFMA) serialized per wave; all 8 waves in ONE barrier domain align
// their bursts -> pipes alternate. r20 (in-wave overlap) spilled. Fix:
// two INDEPENDENT 256-thr blocks per CU (LDS exactly 80 KB each = 160 pool);
// while one block's waves wait in read/waitcnt, the other's feed MFMA
// (m114 TLP mechanism). BM=64, 4 waves (1Mx4N), tile BN=256, walks all 8
// N-tiles -> block owns full rows -> direct out write, reduce dispatch gone.
// Slot = K32 unit, 5 loads (A1 + B4); steady VMC(10) = 2 slots in flight;
// r19 ledger invariant transcribed (enter phase p with slots p+1,p+2 in
// flight; VMC lands p+1; WAR = 1-phase distance guarded by LGKM0+end-BAR).
// Bias in regs; tile-boundary reload enters the counted stream at P15 as
// {bias4, stage5, VMC(10)} -> retires oldest 9 = slot(5)+bias(4), exact.
// ===========================================================================

// ---------------------------------------------------------------------------
// prep: one dispatch, region-decoded by blockIdx.x (unchanged from r20)
// ---------------------------------------------------------------------------
__global__ __launch_bounds__(256) void prep_kernel(
    const float* __restrict__ w1, const float4* __restrict__ w2f,
    const float4* __restrict__ xf, const float* __restrict__ b1,
    const float* __restrict__ b2,
    unsigned short* __restrict__ w1t, ushort4* __restrict__ w2b,
    ushort4* __restrict__ xb, float* __restrict__ bp) {
    const int blk = blockIdx.x;
    const int t   = threadIdx.x;
    if (blk < 512) {
        __shared__ float tile[32][33];
        const int tileI = blk & 15;
        const int tileH = blk >> 4;
        const int iBase = tileI * 32, hBase = tileH * 32;
        const int col = t & 31, rowq = t >> 5;
#pragma unroll
        for (int p = 0; p < 4; ++p) {
            const int row = p * 8 + rowq;
            tile[row][col] = w1[(size_t)(hBase + row) * DIN + iBase + col];
        }
        __syncthreads();
#pragma unroll
        for (int p = 0; p < 4; ++p) {
            const int row = p * 8 + rowq;
            w1t[(size_t)(iBase + row) * DHID + hBase + col] = f2bf(tile[col][row]);
        }
    } else if (blk < 2560) {
        __shared__ float wsum[4];
        const int o = blk - 512;
        const size_t g = (size_t)o * 256 + t;
        float4 v = w2f[g];
        ushort4 ob;
        ob.x = f2bf(v.x); ob.y = f2bf(v.y); ob.z = f2bf(v.z); ob.w = f2bf(v.w);
        w2b[g] = ob;
        float4 bv = ((const float4*)b1)[t];
        float s = v.x * bv.x + v.y * bv.y + v.z * bv.z + v.w * bv.w;
#pragma unroll
        for (int off = 1; off < 64; off <<= 1) s += __shfl_xor(s, off);
        if ((t & 63) == 0) wsum[t >> 6] = s;
        __syncthreads();
        if (t == 0) bp[o] = wsum[0] + wsum[1] + wsum[2] + wsum[3] + b2[o];
    } else {
        // 4096 blocks x 256 thr x 4 float4 = 4194304 float4 groups
        const size_t base = (size_t)(blk - 2560) * 1024 + t;
#pragma unroll
        for (int i = 0; i < 4; ++i) {
            float4 v = xf[base + i * 256];
            ushort4 o;
            o.x = f2bf(v.x); o.y = f2bf(v.y); o.z = f2bf(v.z); o.w = f2bf(v.w);
            xb[base + i * 256] = o;
        }
    }
}

// ---------------------------------------------------------------------------
// gemmW: W[o,i] = sum_h w2b[o,h] * w1t[i,h]. (unchanged)
// ---------------------------------------------------------------------------
__global__ __launch_bounds__(256) void gemmW_kernel(
    const unsigned short* __restrict__ A,
    const unsigned short* __restrict__ Bw,
    unsigned short* __restrict__ W) {
    constexpr int K = DHID;
    __shared__ __align__(16) unsigned short sA[64 * 128];
    __shared__ __align__(16) unsigned short sB[64 * 128];

    const int tid  = threadIdx.x;
    const int lane = tid & 63;
    const int wid  = tid >> 6;
    const int wr = wid >> 1, wc = wid & 1;
    const int r = lane & 15, q = lane >> 4;
    const int blockN = blockIdx.x * 64;
    const int blockM = blockIdx.y * 64;

    const int chKey = (tid & 15) ^ ((tid >> 4) & 15);
    const size_t aBase = (size_t)(blockM + (tid >> 4)) * K + chKey * 8;
    const size_t bBase = (size_t)(blockN + (tid >> 4)) * K + chKey * 8;

    f32x4 acc[2][2];
#pragma unroll
    for (int mt = 0; mt < 2; ++mt)
#pragma unroll
        for (int nt = 0; nt < 2; ++nt) { f32x4 z = {0.f, 0.f, 0.f, 0.f}; acc[mt][nt] = z; }

    for (int k0 = 0; k0 < K; k0 += 128) {
#pragma unroll
        for (int j = 0; j < 4; ++j) {
            gload_lds16(A  + aBase + (size_t)j * 16 * K + k0, sA + j * 2048 + wid * 512);
            gload_lds16(Bw + bBase + (size_t)j * 16 * K + k0, sB + j * 2048 + wid * 512);
        }
        __syncthreads();
#pragma unroll
        for (int ks = 0; ks < 4; ++ks) {
            const int ch = ((ks << 2) + q) ^ r;
            bf16x8 af[2], bf[2];
#pragma unroll
            for (int mt = 0; mt < 2; ++mt) af[mt] = *(const bf16x8*)&sA[(wr * 32 + mt * 16 + r) * 128 + ch * 8];
#pragma unroll
            for (int nt = 0; nt < 2; ++nt) bf[nt] = *(const bf16x8*)&sB[(wc * 32 + nt * 16 + r) * 128 + ch * 8];
#pragma unroll
            for (int mt = 0; mt < 2; ++mt)
#pragma unroll
                for (int nt = 0; nt < 2; ++nt)
                    acc[mt][nt] = __builtin_amdgcn_mfma_f32_16x16x32_bf16(af[mt], bf[nt], acc[mt][nt], 0, 0, 0);
        }
        __syncthreads();
    }

#pragma unroll
    for (int mt = 0; mt < 2; ++mt) {
        const int row0 = blockM + wr * 32 + mt * 16 + q * 4;
#pragma unroll
        for (int nt = 0; nt < 2; ++nt) {
            const int col = blockN + wc * 32 + nt * 16 + r;
#pragma unroll
            for (int reg = 0; reg < 4; ++reg)
                W[(size_t)(row0 + reg) * DIN + col] = f2bf(acc[mt][nt][reg]);
        }
    }
}

// ---------------------------------------------------------------------------
// gemmS r21: 512 blocks x 256 thr (4 waves = 1M x 4N), BM=64, 8 N-tiles of
// 256 cols, 16 slots/tile (slot = K32 unit). LDS 80 KB exactly:
//   A units (64x32k = 2048 sh) at reg*2048            [0, 8192)
//   B units (256x32k = 8192 sh) at 8192 + reg*8192    [8192, 40960)
// Stage: A = 1 gload (row=tid>>2, chunk=tid&3), B = 4 gloads (row j*64+...).
// Pre-swizzled source: global chunk = (tid&3)^((tid>>3)&3); frag read chunk
// q^((r>>1)&3) -> 2-way bank alias (free). Region of slot u = u&3.
// ---------------------------------------------------------------------------
__global__ __launch_bounds__(256, 2) void gemmS_kernel(
    const unsigned short* __restrict__ A,   // xb bf16 [BATCH, DIN]
    const unsigned short* __restrict__ Bw,  // W bf16 [DOUT, DIN]
    const float* __restrict__ bp,           // b' [DOUT]
    float* __restrict__ out) {              // [BATCH]
    constexpr int K = DIN;                   // 512
    __shared__ __align__(16) unsigned short lds[40960];  // 80 KB

    const int tid  = threadIdx.x;            // 0..255
    const int lane = tid & 63;
    const int wid  = tid >> 6;               // 0..3 == wave's N position
    const int r    = lane & 15, q = lane >> 4;

    // 512 blocks = 8 xcd x 64; per XCD 64 blocks x 64 rows = 4096 rows.
    const int b    = blockIdx.x;
    const int xcd  = b & 7;
    const int j    = b >> 3;                 // 0..63
    const int blockM = (xcd * 64 + j) * 64;

    // staging addresses (pre-swizzled global source)
    const int sRow = tid >> 2;               // 0..63
    const int swz  = (tid & 3) ^ ((tid >> 3) & 3);
    const unsigned short* aSrc = A  + (size_t)(blockM + sRow) * K + swz * 8;
    const unsigned short* bSrc = Bw + (size_t)sRow * K + swz * 8;

#define STAGE_A(reg, kt) \
    gload_lds16(aSrc + (kt) * 32, lds + (reg) * 2048 + wid * 512)
#define STAGE_B(bT, reg, kt) do {                                               \
    gload_lds16((bT) + (size_t)(0 * 64) * K + (kt) * 32,                        \
                lds + 8192 + (reg) * 8192 + 0 * 2048 + wid * 512);              \
    gload_lds16((bT) + (size_t)(1 * 64) * K + (kt) * 32,                        \
                lds + 8192 + (reg) * 8192 + 1 * 2048 + wid * 512);              \
    gload_lds16((bT) + (size_t)(2 * 64) * K + (kt) * 32,                        \
                lds + 8192 + (reg) * 8192 + 2 * 2048 + wid * 512);              \
    gload_lds16((bT) + (size_t)(3 * 64) * K + (kt) * 32,                        \
                lds + 8192 + (reg) * 8192 + 3 * 2048 + wid * 512);              \
} while (0)

    // fragment read bases (swizzled chunk)
    const int fOff = (q ^ ((r >> 1) & 3)) * 8;
    const unsigned short* ldsAf = lds + r * 32 + fOff;                 // +reg*2048, +mt*512
    const unsigned short* ldsBf = lds + 8192 + (wid * 64 + r) * 32 + fOff;  // +reg*8192, +nt*512

    f32x4 acc[4][4];
#pragma unroll
    for (int mt = 0; mt < 4; ++mt)
#pragma unroll
        for (int nt = 0; nt < 4; ++nt) { f32x4 z = {0.f, 0.f, 0.f, 0.f}; acc[mt][nt] = z; }
    float mx[4][4];
#pragma unroll
    for (int mt = 0; mt < 4; ++mt)
#pragma unroll
        for (int rg = 0; rg < 4; ++rg) mx[mt][rg] = -INFINITY;
    bf16x8 af[4], bfr[4];
    float bvc[4], bvn[4];

#define RD(reg) do {                                                            \
    const unsigned short* pa_ = ldsAf + (reg) * 2048;                           \
    af[0] = *(const bf16x8*)(pa_);                                              \
    af[1] = *(const bf16x8*)(pa_ + 512);                                        \
    af[2] = *(const bf16x8*)(pa_ + 1024);                                       \
    af[3] = *(const bf16x8*)(pa_ + 1536);                                       \
    const unsigned short* pb_ = ldsBf + (reg) * 8192;                           \
    bfr[0] = *(const bf16x8*)(pb_);                                             \
    bfr[1] = *(const bf16x8*)(pb_ + 512);                                       \
    bfr[2] = *(const bf16x8*)(pb_ + 1024);                                      \
    bfr[3] = *(const bf16x8*)(pb_ + 1536);                                      \
} while (0)
#define MM() do {                                                               \
    __builtin_amdgcn_s_setprio(1);                                              \
    _Pragma("unroll") for (int m_ = 0; m_ < 4; ++m_)                            \
    _Pragma("unroll") for (int n_ = 0; n_ < 4; ++n_)                            \
        acc[m_][n_] = __builtin_amdgcn_mfma_f32_16x16x32_bf16(                  \
            af[m_], bfr[n_], acc[m_][n_], 0, 0, 0);                             \
    __builtin_amdgcn_s_setprio(0);                                              \
} while (0)
#define BAR()   __builtin_amdgcn_s_barrier()
#define LGKM0() asm volatile("s_waitcnt lgkmcnt(0)" ::: "memory")
#define VMC(n)  asm volatile("s_waitcnt vmcnt(" #n ")" ::: "memory")

    // Phase: RD slot p | stage slot p+3 | VMC(10) lands slot p+1 | MM | BAR.
#define PH(reg, sreg, skt, bT) do {                                             \
    RD(reg);                                                                    \
    STAGE_A(sreg, skt); STAGE_B(bT, sreg, skt);                                 \
    VMC(10); LGKM0(); MM(); BAR();                                              \
} while (0)
    // P15 variant: bias for next tile BEFORE the stage -> VMC(10) retires
    // oldest 9 = slot(5) + bias(4); sched_barrier pins the issue order.
#define PH15(reg, sreg, skt, bT, bOff) do {                                     \
    RD(reg);                                                                    \
    bvn[0] = bp[(bOff) + wid * 64 + 0 * 16 + r];                                \
    bvn[1] = bp[(bOff) + wid * 64 + 1 * 16 + r];                                \
    bvn[2] = bp[(bOff) + wid * 64 + 2 * 16 + r];                                \
    bvn[3] = bp[(bOff) + wid * 64 + 3 * 16 + r];                                \
    __builtin_amdgcn_sched_barrier(0);                                          \
    STAGE_A(sreg, skt); STAGE_B(bT, sreg, skt);                                 \
    VMC(10); LGKM0(); MM(); BAR();                                              \
} while (0)

#define FOLD() do {                                                             \
    _Pragma("unroll") for (int mt_ = 0; mt_ < 4; ++mt_)                         \
    _Pragma("unroll") for (int rg_ = 0; rg_ < 4; ++rg_) {                       \
        float v_ = fmaxf(fmaxf(acc[mt_][0][rg_] + bvc[0],                       \
                               acc[mt_][1][rg_] + bvc[1]),                      \
                         fmaxf(acc[mt_][2][rg_] + bvc[2],                       \
                               acc[mt_][3][rg_] + bvc[3]));                     \
        mx[mt_][rg_] = fmaxf(mx[mt_][rg_], v_);                                 \
    }                                                                           \
} while (0)
#define ACC_ZERO() do {                                                         \
    _Pragma("unroll") for (int mt_ = 0; mt_ < 4; ++mt_)                         \
    _Pragma("unroll") for (int nt_ = 0; nt_ < 4; ++nt_) {                       \
        f32x4 z_ = {0.f, 0.f, 0.f, 0.f}; acc[mt_][nt_] = z_;                    \
    }                                                                           \
} while (0)

    // Bias for tile 0; drain so the counted ledger starts clean.
#pragma unroll
    for (int nt = 0; nt < 4; ++nt) bvc[nt] = bp[wid * 64 + nt * 16 + r];
    VMC(0);

    // Prologue: stage slots 0,1,2 (15 loads); VMC(10) lands slot 0.
    STAGE_A(0, 0); STAGE_B(bSrc, 0, 0);
    STAGE_A(1, 1); STAGE_B(bSrc, 1, 1);
    STAGE_A(2, 2); STAGE_B(bSrc, 2, 2);
    VMC(10);
    BAR();

#pragma unroll 1
    for (int t = 0; t < 7; ++t) {
        const unsigned short* bT  = bSrc + (size_t)t * 256 * K;
        const unsigned short* bTn = bT + (size_t)256 * K;
        PH(0, 3, 3, bT);
        PH(1, 0, 4, bT);
        PH(2, 1, 5, bT);
        PH(3, 2, 6, bT);
        PH(0, 3, 7, bT);
        PH(1, 0, 8, bT);
        PH(2, 1, 9, bT);
        PH(3, 2, 10, bT);
        PH(0, 3, 11, bT);
        PH(1, 0, 12, bT);
        PH(2, 1, 13, bT);
        PH(3, 2, 14, bT);
        PH(0, 3, 15, bT);
        PH(1, 0, 0, bTn);
        PH(2, 1, 1, bTn);
        PH15(3, 2, 2, bTn, (t + 1) * 256);
        FOLD();
        ACC_ZERO();
#pragma unroll
        for (int nt = 0; nt < 4; ++nt) bvc[nt] = bvn[nt];
    }
    // ---- tile 7 (drain) ----
    {
        const unsigned short* bT = bSrc + (size_t)7 * 256 * K;
        PH(0, 3, 3, bT);
        PH(1, 0, 4, bT);
        PH(2, 1, 5, bT);
        PH(3, 2, 6, bT);
        PH(0, 3, 7, bT);
        PH(1, 0, 8, bT);
        PH(2, 1, 9, bT);
        PH(3, 2, 10, bT);
        PH(0, 3, 11, bT);
        PH(1, 0, 12, bT);
        PH(2, 1, 13, bT);
        PH(3, 2, 14, bT);
        PH(0, 3, 15, bT);
        RD(1); VMC(5); LGKM0(); MM(); BAR();
        RD(2); VMC(0); LGKM0(); MM(); BAR();
        RD(3); LGKM0(); MM();
        FOLD();
    }

#undef STAGE_A
#undef STAGE_B
#undef RD
#undef MM
#undef BAR
#undef LGKM0
#undef VMC
#undef PH
#undef PH15
#undef FOLD
#undef ACC_ZERO

    // Final: cross-wave (4 N-waves) max via LDS, then direct out write.
    __syncthreads();
    float* smax = (float*)lds;   // 64 rows x 4 waves = 1 KB (reuses A region)
#pragma unroll
    for (int mt = 0; mt < 4; ++mt) {
#pragma unroll
        for (int rg = 0; rg < 4; ++rg) {
            float v = mx[mt][rg];
#pragma unroll
            for (int off = 1; off < 16; off <<= 1)
                v = fmaxf(v, __shfl_xor(v, off));
            if (r == 0) smax[(mt * 16 + q * 4 + rg) * 4 + wid] = v;
        }
    }
    __syncthreads();
    if (tid < 64) {
        const float* p = smax + tid * 4;
        out[blockM + tid] = fmaxf(fmaxf(p[0], p[1]), fmaxf(p[2], p[3]));
    }
}

// ---------------------------------------------------------------------------
extern "C" void kernel_launch(void* const* d_in, const int* in_sizes, int n_in,
                              void* d_out, int out_size, void* d_ws, size_t ws_size,
                              hipStream_t stream) {
    const float* x   = (const float*)d_in[0];
    const float* l1w = (const float*)d_in[1];
    const float* l1b = (const float*)d_in[2];
    const float* w2  = (const float*)d_in[3];
    const float* b2  = (const float*)d_in[4];
    float* out = (float*)d_out;

    char* ws = (char*)d_ws;
    unsigned short* w1t = (unsigned short*)(ws);                 //  1 MB  w1^T bf16 [512,1024]
    unsigned short* w2b = (unsigned short*)(ws + 1048576);       //  4 MB  w2 bf16 [2048,1024]
    unsigned short* Wb  = (unsigned short*)(ws + 5242880);       //  2 MB  W bf16 [2048,512]
    float* bp           = (float*)(ws + 7340032);                //  8 KB  b' fp32 [2048]
    unsigned short* xb  = (unsigned short*)(ws + 7348224);       // 32 MB  x bf16 [32768,512]

    // 1) fused pre-work: w1 transpose + w2 cvt(+bgemv) + x cvt
    prep_kernel<<<6656, 256, 0, stream>>>(
        l1w, (const float4*)w2, (const float4*)x, l1b, b2,
        w1t, (ushort4*)w2b, (ushort4*)xb, bp);

    // 2) W = w2b @ w1t^T  [2048, 512]
    gemmW_kernel<<<dim3(DIN / 64, DOUT / 64), 256, 0, stream>>>(w2b, w1t, Wb);

    // 3) scores = xb @ W^T + b', fused row-max, direct out (2 blocks/CU)
    gemmS_kernel<<<512, 256, 0, stream>>>(xb, Wb, bp, out);
}